// Round 3
// baseline (4271.893 us; speedup 1.0000x reference)
//
#include <hip/hip_runtime.h>
#include <math.h>

#define NN 50000
#define EE 800000
#define HH 128
#define AHD 64
#define KIT 10
#define NHF (NN * HH)     // 6,400,000 floats per snapshot
#define SS  (NN * 16)     // slice stride in floats (16 features per slice)

__device__ __forceinline__ float gelu_exact(float x) {
  return 0.5f * x * (1.f + erff(x * 0.70710678118654752f));
}

// ---------------- graph preprocessing ----------------
__global__ __launch_bounds__(256) void zero_kernel(float* __restrict__ wsum,
                                                   int* __restrict__ deg, int n) {
  int i = blockIdx.x * 256 + threadIdx.x;
  if (i < n) { wsum[i] = 0.f; deg[i] = 0; }
}

__global__ __launch_bounds__(256) void edge_stats_kernel(const int* __restrict__ ei,
                                                         const float* __restrict__ ew,
                                                         float* __restrict__ wsum,
                                                         int* __restrict__ deg, int e_cnt) {
  int e = blockIdx.x * 256 + threadIdx.x;
  if (e >= e_cnt) return;
  atomicAdd(&wsum[ei[e]], ew[e]);       // sum of outgoing edge weights by source (row)
  atomicAdd(&deg[ei[EE + e]], 1);       // in-degree by destination (col)
}

// multi-block scan: block sums -> scan partials -> local writeback
__global__ __launch_bounds__(256) void scan1_kernel(const int* __restrict__ deg,
                                                    int* __restrict__ bsum, int n) {
  __shared__ int red[256];
  int i = blockIdx.x * 256 + threadIdx.x;
  red[threadIdx.x] = (i < n) ? deg[i] : 0;
  __syncthreads();
  for (int off = 128; off > 0; off >>= 1) {
    if (threadIdx.x < off) red[threadIdx.x] += red[threadIdx.x + off];
    __syncthreads();
  }
  if (threadIdx.x == 0) bsum[blockIdx.x] = red[0];
}

__global__ __launch_bounds__(256) void scan2_kernel(const int* __restrict__ bsum,
                                                    int* __restrict__ boff,
                                                    int* __restrict__ row_start, int nb, int n) {
  __shared__ int buf[256];
  int tid = threadIdx.x;
  int v = (tid < nb) ? bsum[tid] : 0;
  buf[tid] = v;
  __syncthreads();
  for (int off = 1; off < 256; off <<= 1) {
    int t = (tid >= off) ? buf[tid - off] : 0;
    __syncthreads();
    buf[tid] += t;
    __syncthreads();
  }
  if (tid < nb) boff[tid] = buf[tid] - v;  // exclusive prefix
  if (tid == 255) row_start[n] = buf[255];
}

__global__ __launch_bounds__(256) void scan3_kernel(const int* __restrict__ deg,
                                                    const int* __restrict__ boff,
                                                    int* __restrict__ row_start,
                                                    int* __restrict__ cursor, int n) {
  __shared__ int buf[256];
  int tid = threadIdx.x;
  int i = blockIdx.x * 256 + tid;
  int v = (i < n) ? deg[i] : 0;
  buf[tid] = v;
  __syncthreads();
  for (int off = 1; off < 256; off <<= 1) {
    int t = (tid >= off) ? buf[tid - off] : 0;
    __syncthreads();
    buf[tid] += t;
    __syncthreads();
  }
  if (i < n) {
    int ex = boff[blockIdx.x] + buf[tid] - v;
    row_start[i] = ex;
    cursor[i] = ex;
  }
}

__global__ __launch_bounds__(256) void csr_fill_kernel(const int* __restrict__ ei,
                                                       const float* __restrict__ ew,
                                                       const float* __restrict__ wsum,
                                                       int* __restrict__ cursor,
                                                       int2* __restrict__ csr, int e_cnt) {
  int e = blockIdx.x * 256 + threadIdx.x;
  if (e >= e_cnt) return;
  int r = ei[e], c = ei[EE + e];
  float ws = wsum[r];
  ws = ws < 1.f ? 1.f : ws;
  float v = 0.9f * ew[e] / ws;            // (1-ALPHA) * enorm folded together
  int pos = atomicAdd(&cursor[c], 1);
  csr[pos] = make_int2(r, __float_as_int(v));
}

// ---------------- propagation: XCD-sliced feature layout ----------------
// h stored as hS[slice 0..7][node][16 floats]; slice table = 3.2MB < 4MB per-XCD L2.
// blockIdx & 7 -> slice, so (with round-robin block->XCD dispatch) each XCD's L2
// holds its own slice. Wave = 4 edge-groups x 16 features; CSR/base loads are
// non-temporal to avoid evicting the h slice.
__global__ __launch_bounds__(256, 8) void prop_kernel(const float* __restrict__ hS,
                                                      const float* __restrict__ baseS,
                                                      const int* __restrict__ row_start,
                                                      const long* __restrict__ csr,
                                                      float* __restrict__ hnS) {
  int slice = blockIdx.x & 7;
  int wave = threadIdx.x >> 6;
  int node = __builtin_amdgcn_readfirstlane((blockIdx.x >> 3) * 4 + wave);
  if (node >= NN) return;
  int lane = threadIdx.x & 63;
  int g = lane >> 4, f = lane & 15;
  const float* hc = hS + (size_t)slice * SS;
  int s = row_start[node], e = row_start[node + 1];
  float acc0 = 0.f, acc1 = 0.f;
  int i = s + g;
  for (; i + 4 < e; i += 8) {
    long e0 = __builtin_nontemporal_load(&csr[i]);
    long e1 = __builtin_nontemporal_load(&csr[i + 4]);
    float h0 = hc[(size_t)((int)e0) * 16 + f];
    float h1 = hc[(size_t)((int)e1) * 16 + f];
    acc0 = fmaf(__int_as_float((int)(e0 >> 32)), h0, acc0);
    acc1 = fmaf(__int_as_float((int)(e1 >> 32)), h1, acc1);
  }
  if (i < e) {
    long e0 = __builtin_nontemporal_load(&csr[i]);
    acc0 = fmaf(__int_as_float((int)(e0 >> 32)), hc[(size_t)((int)e0) * 16 + f], acc0);
  }
  float acc = acc0 + acc1;
  acc += __shfl_xor(acc, 16);
  acc += __shfl_xor(acc, 32);
  if (g == 0) {
    size_t o = (size_t)slice * SS + (size_t)node * 16 + f;
    float b = __builtin_nontemporal_load(&baseS[o]);
    hnS[o] = fmaf(0.1f, b, acc);
  }
}

// ---------------- dense: out[n][j] = act(sum_k X[n][k] * W[j][k] + ...) ----------------
// Register-tiled SGEMM: block 256 threads, tile 64 rows x JP cols.
// Thread (tx=tid&15, ty=tid>>4): 4 rows x CT=JP/16 cols. X transposed + W staged
// in LDS; per k: 3 ds_read_b128 vs 32 FMA (JP=128) -> VALU-bound.
// AMODE: 0 = row-major input, 1 = sliced [s][n][16] input. OUTS: sliced output.
#define DKC 32
#define DRT 64
template <int K, int KA, int JP, int JR, int ACT, bool RESID, int AMODE, bool OUTS>
__global__ __launch_bounds__(256, 4) void dense_kernel(
    const float* __restrict__ Xa, const float* __restrict__ Xb,
    const float* __restrict__ W, const float* __restrict__ lb,
    const float* __restrict__ bg, const float* __restrict__ bb,
    const float* __restrict__ bm, const float* __restrict__ bv,
    const float* __restrict__ resid, float* __restrict__ out) {
  static_assert(K % DKC == 0 && JP % 16 == 0, "");
  constexpr int CT = JP / 16;
  __shared__ float xT[DKC][DRT + 4];
  __shared__ float wT[DKC][JP + 4];
  const int tid = threadIdx.x;
  const int tx = tid & 15, ty = tid >> 4;
  const int r0 = blockIdx.x * DRT;

  float acc[4][CT];
#pragma unroll
  for (int r = 0; r < 4; ++r)
#pragma unroll
    for (int c = 0; c < CT; ++c) acc[r][c] = 0.f;

  for (int kc = 0; kc < K; kc += DKC) {
    __syncthreads();
    // stage X transposed: xT[k][r]
    for (int idx = tid; idx < DRT * (DKC / 4); idx += 256) {
      int r = idx >> 3;            // DKC/4 == 8
      int c4 = (idx & 7) * 4;
      int row = r0 + r;
      int col = kc + c4;
      float4 v = make_float4(0.f, 0.f, 0.f, 0.f);
      if (row < NN) {
        if (AMODE == 0) {
          if (col < KA) v = *(const float4*)&Xa[(size_t)row * KA + col];
          else          v = *(const float4*)&Xb[(size_t)row * (K - KA) + (col - KA)];
        } else {
          const float* src = (col < KA) ? Xa : Xb;
          int c = (col < KA) ? col : col - KA;
          v = *(const float4*)&src[(size_t)(c >> 4) * SS + (size_t)row * 16 + (c & 15)];
        }
      }
      xT[c4 + 0][r] = v.x; xT[c4 + 1][r] = v.y;
      xT[c4 + 2][r] = v.z; xT[c4 + 3][r] = v.w;
    }
    // stage W: wT[k][j]
    for (int idx = tid; idx < JP * (DKC / 4); idx += 256) {
      int j = idx >> 3;
      int c4 = (idx & 7) * 4;
      float4 v = make_float4(0.f, 0.f, 0.f, 0.f);
      if (j < JR) v = *(const float4*)&W[(size_t)j * K + kc + c4];
      wT[c4 + 0][j] = v.x; wT[c4 + 1][j] = v.y;
      wT[c4 + 2][j] = v.z; wT[c4 + 3][j] = v.w;
    }
    __syncthreads();
#pragma unroll 4
    for (int k = 0; k < DKC; ++k) {
      float4 xf = *(const float4*)&xT[k][tx * 4];
      float wf[CT];
      if (CT % 4 == 0) {
#pragma unroll
        for (int c = 0; c < CT; c += 4) {
          float4 wv = *(const float4*)&wT[k][ty * CT + c];
          wf[c] = wv.x; wf[c + 1] = wv.y; wf[c + 2] = wv.z; wf[c + 3] = wv.w;
        }
      } else {
#pragma unroll
        for (int c = 0; c < CT; ++c) wf[c] = wT[k][ty * CT + c];
      }
      float xr[4] = {xf.x, xf.y, xf.z, xf.w};
#pragma unroll
      for (int r = 0; r < 4; ++r)
#pragma unroll
        for (int c = 0; c < CT; ++c) acc[r][c] = fmaf(xr[r], wf[c], acc[r][c]);
    }
  }
  // epilogue
#pragma unroll
  for (int c = 0; c < CT; ++c) {
    int j = ty * CT + c;
    if (j >= JR) continue;
    float sc = 0.f, sh = 0.f;
    if (ACT == 1) {
      sc = bg[j] * rsqrtf(bv[j] + 1e-5f);
      sh = (lb[j] - bm[j]) * sc + bb[j];
    } else {
      sh = lb[j];
    }
#pragma unroll
    for (int r = 0; r < 4; ++r) {
      int row = r0 + tx * 4 + r;
      if (row >= NN) continue;
      float a = acc[r][c];
      float y;
      if (ACT == 0)      y = a + sh;
      else if (ACT == 1) y = fmaxf(fmaf(a, sc, sh), 0.f);
      else               y = gelu_exact(a + sh);
      if (RESID) y += resid[(size_t)row * JR + j];
      if (OUTS) out[(size_t)(j >> 4) * SS + (size_t)row * 16 + (j & 15)] = y;
      else      out[(size_t)row * JR + j] = y;
    }
  }
}

// ---------------- att2 (64 -> 11) + softmax, one thread per node ----------------
__global__ __launch_bounds__(64) void att2_softmax_kernel(const float* __restrict__ g,
                                                          const float* __restrict__ W2,
                                                          const float* __restrict__ b2,
                                                          float* __restrict__ attw, int n_rows) {
  __shared__ float gl[64][65];
  int r0 = blockIdx.x * 64;
  for (int idx = threadIdx.x; idx < 64 * 16; idx += 64) {
    int r = idx >> 4, c4 = (idx & 15) * 4;
    float4 v = make_float4(0.f, 0.f, 0.f, 0.f);
    if (r0 + r < n_rows) v = *(const float4*)&g[(size_t)(r0 + r) * 64 + c4];
    gl[r][c4] = v.x; gl[r][c4 + 1] = v.y; gl[r][c4 + 2] = v.z; gl[r][c4 + 3] = v.w;
  }
  __syncthreads();
  int r = threadIdx.x;
  int n = r0 + r;
  if (n >= n_rows) return;
  float a[KIT + 1];
#pragma unroll
  for (int j = 0; j < KIT + 1; ++j) {
    float acc = b2[j];
#pragma unroll
    for (int k = 0; k < 64; ++k) acc = fmaf(gl[r][k], W2[j * 64 + k], acc);
    a[j] = acc;
  }
  float m = a[0];
#pragma unroll
  for (int j = 1; j < KIT + 1; ++j) m = fmaxf(m, a[j]);
  float s = 0.f;
#pragma unroll
  for (int j = 0; j < KIT + 1; ++j) { a[j] = expf(a[j] - m); s += a[j]; }
  float inv = 1.f / s;
#pragma unroll
  for (int j = 0; j < KIT + 1; ++j) attw[n * 16 + j] = a[j] * inv;
}

// ---------------- fuse: fused[n][128] = sum_k attw[n][k] * XS_k (sliced) ----------------
__global__ __launch_bounds__(256) void fused_gather_kernel(const float* __restrict__ XS,
                                                           const float* __restrict__ attw,
                                                           float* __restrict__ fused) {
  int tid = threadIdx.x;
  int node = blockIdx.x * 2 + (tid >> 7);
  if (node >= NN) return;
  int f128 = tid & 127;
  int s = f128 >> 4, f = f128 & 15;
  size_t off = (size_t)s * SS + (size_t)node * 16 + f;
  float acc = 0.f;
#pragma unroll
  for (int k = 0; k <= KIT; ++k) {
    float wk = attw[node * 16 + k];
    acc = fmaf(wk, XS[(size_t)k * NHF + off], acc);
  }
  fused[(size_t)node * HH + f128] = acc;
}

// recompute-path variant: fused (+)= attw[:,k] * h (h sliced)
__global__ __launch_bounds__(256) void fused_accum_kernel(const float* __restrict__ hSl,
                                                          const float* __restrict__ attw,
                                                          float* __restrict__ fused, int k) {
  int tid = threadIdx.x;
  int node = blockIdx.x * 2 + (tid >> 7);
  if (node >= NN) return;
  int f128 = tid & 127;
  int s = f128 >> 4, f = f128 & 15;
  float wk = attw[node * 16 + k];
  float v = hSl[(size_t)s * SS + (size_t)node * 16 + f];
  size_t o = (size_t)node * HH + f128;
  if (k == 0) fused[o] = wk * v;
  else        fused[o] = fmaf(wk, v, fused[o]);
}

extern "C" void kernel_launch(void* const* d_in, const int* in_sizes, int n_in,
                              void* d_out, int out_size, void* d_ws, size_t ws_size,
                              hipStream_t stream) {
  (void)in_sizes; (void)n_in; (void)out_size;
  const float* x      = (const float*)d_in[0];
  const int*   ei     = (const int*)d_in[1];
  const float* ew     = (const float*)d_in[2];
  const float* lin1_w = (const float*)d_in[3];
  const float* lin1_b = (const float*)d_in[4];
  const float* bn1_g  = (const float*)d_in[5];
  const float* bn1_b  = (const float*)d_in[6];
  const float* bn1_m  = (const float*)d_in[7];
  const float* bn1_v  = (const float*)d_in[8];
  const float* lin2_w = (const float*)d_in[9];
  const float* lin2_b = (const float*)d_in[10];
  const float* bn2_g  = (const float*)d_in[11];
  const float* bn2_b  = (const float*)d_in[12];
  const float* bn2_m  = (const float*)d_in[13];
  const float* bn2_v  = (const float*)d_in[14];
  const float* att1_w = (const float*)d_in[15];
  const float* att1_b = (const float*)d_in[16];
  const float* att2_w = (const float*)d_in[17];
  const float* att2_b = (const float*)d_in[18];
  const float* head1_w= (const float*)d_in[19];
  const float* head1_b= (const float*)d_in[20];
  const float* bn3_g  = (const float*)d_in[21];
  const float* bn3_b  = (const float*)d_in[22];
  const float* bn3_m  = (const float*)d_in[23];
  const float* bn3_v  = (const float*)d_in[24];
  const float* head2_w= (const float*)d_in[25];
  const float* head2_b= (const float*)d_in[26];
  float* out = (float*)d_out;

  char* p = (char*)d_ws;
  auto alloc = [&](size_t bytes) -> void* {
    void* r = (void*)p;
    p += (bytes + 255) & ~(size_t)255;
    return r;
  };
  float* wsum     = (float*)alloc((size_t)NN * 4);
  int*   deg      = (int*)alloc((size_t)NN * 4);
  int*   row_start= (int*)alloc((size_t)(NN + 1) * 4);
  int*   cursor   = (int*)alloc((size_t)NN * 4);
  int*   bsum     = (int*)alloc((size_t)256 * 4);
  int*   boff     = (int*)alloc((size_t)256 * 4);
  long*  csr      = (long*)alloc((size_t)EE * 8);
  float* gbuf     = (float*)alloc((size_t)NN * AHD * 4);
  float* attw     = (float*)alloc((size_t)NN * 16 * 4);
  float* fused    = (float*)alloc((size_t)NN * HH * 4);  // also stem h1 (row-major)
  float* zbuf     = (float*)alloc((size_t)NN * AHD * 4);
  size_t common = (size_t)(p - (char*)d_ws);
  size_t stored_need = common + (size_t)(KIT + 1) * NHF * 4 + 4096;
  bool stored = ws_size >= stored_need;

  const int GE = (EE + 255) / 256;         // edge-parallel grid
  const int GN = (NN + 255) / 256;         // node-parallel grid (196)
  const int GD = (NN + DRT - 1) / DRT;     // dense grid (782)
  const int GP = ((NN + 3) / 4) * 8;       // prop grid: 12500 node-blocks x 8 slices
  const int GF = (NN + 1) / 2;             // fuse grid (25000)
  const int GA = (NN + 63) / 64;           // att2 grid

  // graph preprocessing
  zero_kernel<<<GN, 256, 0, stream>>>(wsum, deg, NN);
  edge_stats_kernel<<<GE, 256, 0, stream>>>(ei, ew, wsum, deg, EE);
  scan1_kernel<<<GN, 256, 0, stream>>>(deg, bsum, NN);
  scan2_kernel<<<1, 256, 0, stream>>>(bsum, boff, row_start, GN, NN);
  scan3_kernel<<<GN, 256, 0, stream>>>(deg, boff, row_start, cursor, NN);
  csr_fill_kernel<<<GE, 256, 0, stream>>>(ei, ew, wsum, cursor, (int2*)csr, EE);

  if (stored) {
    float* XS = (float*)alloc((size_t)(KIT + 1) * NHF * 4);  // sliced snapshots; XS0 = base
    // stem: h1 -> fused (row-major), base -> XS slot 0 (sliced)
    dense_kernel<128, 128, 128, 128, 1, false, 0, false><<<GD, 256, 0, stream>>>(
        x, nullptr, lin1_w, lin1_b, bn1_g, bn1_b, bn1_m, bn1_v, nullptr, fused);
    dense_kernel<128, 128, 128, 128, 1, true, 0, true><<<GD, 256, 0, stream>>>(
        fused, nullptr, lin2_w, lin2_b, bn2_g, bn2_b, bn2_m, bn2_v, fused, XS);
    for (int k = 0; k < KIT; ++k) {
      prop_kernel<<<GP, 256, 0, stream>>>(XS + (size_t)k * NHF, XS, row_start,
                                          csr, XS + (size_t)(k + 1) * NHF);
    }
    // attention: ctx = [xs0, xs10] (both sliced)
    dense_kernel<256, 128, 64, 64, 2, false, 1, false><<<GD, 256, 0, stream>>>(
        XS, XS + (size_t)KIT * NHF, att1_w, att1_b, nullptr, nullptr, nullptr, nullptr,
        nullptr, gbuf);
    att2_softmax_kernel<<<GA, 64, 0, stream>>>(gbuf, att2_w, att2_b, attw, NN);
    fused_gather_kernel<<<GF, 256, 0, stream>>>(XS, attw, fused);
  } else {
    float* base = (float*)alloc((size_t)NHF * 4);  // sliced
    float* hA   = (float*)alloc((size_t)NHF * 4);
    float* hB   = (float*)alloc((size_t)NHF * 4);
    dense_kernel<128, 128, 128, 128, 1, false, 0, false><<<GD, 256, 0, stream>>>(
        x, nullptr, lin1_w, lin1_b, bn1_g, bn1_b, bn1_m, bn1_v, nullptr, fused);
    dense_kernel<128, 128, 128, 128, 1, true, 0, true><<<GD, 256, 0, stream>>>(
        fused, nullptr, lin2_w, lin2_b, bn2_g, bn2_b, bn2_m, bn2_v, fused, base);
    const float* cur = base;
    for (int k = 1; k <= KIT; ++k) {
      float* nxt = (k & 1) ? hA : hB;
      prop_kernel<<<GP, 256, 0, stream>>>(cur, base, row_start, csr, nxt);
      cur = nxt;
    }
    dense_kernel<256, 128, 64, 64, 2, false, 1, false><<<GD, 256, 0, stream>>>(
        base, cur, att1_w, att1_b, nullptr, nullptr, nullptr, nullptr, nullptr, gbuf);
    att2_softmax_kernel<<<GA, 64, 0, stream>>>(gbuf, att2_w, att2_b, attw, NN);
    fused_accum_kernel<<<GF, 256, 0, stream>>>(base, attw, fused, 0);
    cur = base;
    for (int k = 1; k <= KIT; ++k) {
      float* nxt = (k & 1) ? hA : hB;
      prop_kernel<<<GP, 256, 0, stream>>>(cur, base, row_start, csr, nxt);
      fused_accum_kernel<<<GF, 256, 0, stream>>>(nxt, attw, fused, k);
      cur = nxt;
    }
  }

  // heads (fused row-major -> zbuf row-major -> out)
  dense_kernel<128, 128, 64, 64, 1, false, 0, false><<<GD, 256, 0, stream>>>(
      fused, nullptr, head1_w, head1_b, bn3_g, bn3_b, bn3_m, bn3_v, nullptr, zbuf);
  dense_kernel<64, 64, 48, 40, 0, false, 0, false><<<GD, 256, 0, stream>>>(
      zbuf, nullptr, head2_w, head2_b, nullptr, nullptr, nullptr, nullptr, nullptr, out);
}

// Round 4
// 777.479 us; speedup vs baseline: 5.4945x; 5.4945x over previous
//
#include <hip/hip_runtime.h>
#include <hip/hip_fp16.h>
#include <math.h>

#define NN 50000
#define EE 800000
#define HH 128
#define AHD 64
#define KIT 10
#define NHF (NN * HH)     // 6,400,000 elements per snapshot

__device__ __forceinline__ float gelu_exact(float x) {
  return 0.5f * x * (1.f + erff(x * 0.70710678118654752f));
}

// typed 4-float load/store helpers (fp32 or fp16 storage)
__device__ __forceinline__ float4 ld4(const float* p) { return *(const float4*)p; }
__device__ __forceinline__ float4 ld4(const __half* p) {
  const __half2* q = (const __half2*)p;
  float2 lo = __half22float2(q[0]);
  float2 hi = __half22float2(q[1]);
  return make_float4(lo.x, lo.y, hi.x, hi.y);
}
__device__ __forceinline__ void st1(float* p, float v) { *p = v; }
__device__ __forceinline__ void st1(__half* p, float v) { *p = __float2half_rn(v); }

// ---------------- graph preprocessing ----------------
__global__ __launch_bounds__(256) void zero_kernel(float* __restrict__ wsum,
                                                   int* __restrict__ deg, int n) {
  int i = blockIdx.x * 256 + threadIdx.x;
  if (i < n) { wsum[i] = 0.f; deg[i] = 0; }
}

__global__ __launch_bounds__(256) void edge_stats_kernel(const int* __restrict__ ei,
                                                         const float* __restrict__ ew,
                                                         float* __restrict__ wsum,
                                                         int* __restrict__ deg, int e_cnt) {
  int e = blockIdx.x * 256 + threadIdx.x;
  if (e >= e_cnt) return;
  atomicAdd(&wsum[ei[e]], ew[e]);       // sum of outgoing edge weights by source (row)
  atomicAdd(&deg[ei[EE + e]], 1);       // in-degree by destination (col)
}

// multi-block scan: block sums -> scan partials -> local writeback
__global__ __launch_bounds__(256) void scan1_kernel(const int* __restrict__ deg,
                                                    int* __restrict__ bsum, int n) {
  __shared__ int red[256];
  int i = blockIdx.x * 256 + threadIdx.x;
  red[threadIdx.x] = (i < n) ? deg[i] : 0;
  __syncthreads();
  for (int off = 128; off > 0; off >>= 1) {
    if (threadIdx.x < off) red[threadIdx.x] += red[threadIdx.x + off];
    __syncthreads();
  }
  if (threadIdx.x == 0) bsum[blockIdx.x] = red[0];
}

__global__ __launch_bounds__(256) void scan2_kernel(const int* __restrict__ bsum,
                                                    int* __restrict__ boff,
                                                    int* __restrict__ row_start, int nb, int n) {
  __shared__ int buf[256];
  int tid = threadIdx.x;
  int v = (tid < nb) ? bsum[tid] : 0;
  buf[tid] = v;
  __syncthreads();
  for (int off = 1; off < 256; off <<= 1) {
    int t = (tid >= off) ? buf[tid - off] : 0;
    __syncthreads();
    buf[tid] += t;
    __syncthreads();
  }
  if (tid < nb) boff[tid] = buf[tid] - v;  // exclusive prefix
  if (tid == 255) row_start[n] = buf[255];
}

__global__ __launch_bounds__(256) void scan3_kernel(const int* __restrict__ deg,
                                                    const int* __restrict__ boff,
                                                    int* __restrict__ row_start,
                                                    int* __restrict__ cursor, int n) {
  __shared__ int buf[256];
  int tid = threadIdx.x;
  int i = blockIdx.x * 256 + tid;
  int v = (i < n) ? deg[i] : 0;
  buf[tid] = v;
  __syncthreads();
  for (int off = 1; off < 256; off <<= 1) {
    int t = (tid >= off) ? buf[tid - off] : 0;
    __syncthreads();
    buf[tid] += t;
    __syncthreads();
  }
  if (i < n) {
    int ex = boff[blockIdx.x] + buf[tid] - v;
    row_start[i] = ex;
    cursor[i] = ex;
  }
}

__global__ __launch_bounds__(256) void csr_fill_kernel(const int* __restrict__ ei,
                                                       const float* __restrict__ ew,
                                                       const float* __restrict__ wsum,
                                                       int* __restrict__ cursor,
                                                       int2* __restrict__ csr, int e_cnt) {
  int e = blockIdx.x * 256 + threadIdx.x;
  if (e >= e_cnt) return;
  int r = ei[e], c = ei[EE + e];
  float ws = wsum[r];
  ws = ws < 1.f ? 1.f : ws;
  float v = 0.9f * ew[e] / ws;            // (1-ALPHA) * enorm folded together
  int pos = atomicAdd(&cursor[c], 1);
  csr[pos] = make_int2(r, __float_as_int(v));
}

// ---------------- propagation: one wave per node, fp16 h, half2 per lane ----------------
// Row gather = 256B coalesced (64 lanes x half2). CSR walked with wave-uniform
// scalar loads; unrolled x8 -> 8 row-gathers in flight per wave.
__global__ __launch_bounds__(256) void prop_kernel(const __half* __restrict__ h_cur,
                                                   const __half* __restrict__ base,
                                                   const int* __restrict__ row_start,
                                                   const long* __restrict__ csr,
                                                   __half* __restrict__ h_next) {
  int node = __builtin_amdgcn_readfirstlane((int)blockIdx.x * 4 + (int)(threadIdx.x >> 6));
  if (node >= NN) return;
  int lane = threadIdx.x & 63;
  const __half2* hc = (const __half2*)h_cur;
  float2 b = __half22float2(((const __half2*)base)[(size_t)node * 64 + lane]);
  float ax = 0.1f * b.x, ay = 0.1f * b.y;   // ALPHA * base
  float bx = 0.f, by = 0.f;
  int s = row_start[node], e = row_start[node + 1];
  int i = s;
  for (; i + 8 <= e; i += 8) {
    long c[8];
#pragma unroll
    for (int j = 0; j < 8; ++j) c[j] = csr[i + j];
    float2 g[8];
#pragma unroll
    for (int j = 0; j < 8; ++j) g[j] = __half22float2(hc[(size_t)(int)c[j] * 64 + lane]);
#pragma unroll
    for (int j = 0; j < 8; ++j) {
      float v = __int_as_float((int)(c[j] >> 32));
      if (j & 1) { bx = fmaf(v, g[j].x, bx); by = fmaf(v, g[j].y, by); }
      else       { ax = fmaf(v, g[j].x, ax); ay = fmaf(v, g[j].y, ay); }
    }
  }
  for (; i + 4 <= e; i += 4) {
    long c[4];
#pragma unroll
    for (int j = 0; j < 4; ++j) c[j] = csr[i + j];
    float2 g[4];
#pragma unroll
    for (int j = 0; j < 4; ++j) g[j] = __half22float2(hc[(size_t)(int)c[j] * 64 + lane]);
#pragma unroll
    for (int j = 0; j < 4; ++j) {
      float v = __int_as_float((int)(c[j] >> 32));
      if (j & 1) { bx = fmaf(v, g[j].x, bx); by = fmaf(v, g[j].y, by); }
      else       { ax = fmaf(v, g[j].x, ax); ay = fmaf(v, g[j].y, ay); }
    }
  }
  for (; i < e; ++i) {
    long c0 = csr[i];
    float2 g0 = __half22float2(hc[(size_t)(int)c0 * 64 + lane]);
    float v = __int_as_float((int)(c0 >> 32));
    ax = fmaf(v, g0.x, ax); ay = fmaf(v, g0.y, ay);
  }
  ((__half2*)h_next)[(size_t)node * 64 + lane] =
      __float22half2_rn(make_float2(ax + bx, ay + by));
}

// ---------------- dense: out[n][j] = act(sum_k X[n][k] * W[j][k] + ...) ----------------
// Register-tiled SGEMM: block 256 threads, tile 64 rows x JP cols.
// Thread (tx=tid&15, ty=tid>>4): 4 rows x CT=JP/16 cols. X transposed + W staged in LDS.
#define DKC 32
#define DRT 64
template <int K, int KA, int JP, int JR, int ACT, bool RESID, typename IT, typename OT>
__global__ __launch_bounds__(256, 4) void dense_kernel(
    const IT* __restrict__ Xa, const IT* __restrict__ Xb,
    const float* __restrict__ W, const float* __restrict__ lb,
    const float* __restrict__ bg, const float* __restrict__ bb,
    const float* __restrict__ bm, const float* __restrict__ bv,
    const float* __restrict__ resid, OT* __restrict__ out) {
  static_assert(K % DKC == 0 && JP % 16 == 0, "");
  constexpr int CT = JP / 16;
  __shared__ float xT[DKC][DRT + 4];
  __shared__ float wT[DKC][JP + 4];
  const int tid = threadIdx.x;
  const int tx = tid & 15, ty = tid >> 4;
  const int r0 = blockIdx.x * DRT;

  float acc[4][CT];
#pragma unroll
  for (int r = 0; r < 4; ++r)
#pragma unroll
    for (int c = 0; c < CT; ++c) acc[r][c] = 0.f;

  for (int kc = 0; kc < K; kc += DKC) {
    __syncthreads();
    // stage X transposed: xT[k][r]
    for (int idx = tid; idx < DRT * (DKC / 4); idx += 256) {
      int r = idx >> 3;            // DKC/4 == 8
      int c4 = (idx & 7) * 4;
      int row = r0 + r;
      int col = kc + c4;
      float4 v = make_float4(0.f, 0.f, 0.f, 0.f);
      if (row < NN) {
        if (col < KA) v = ld4(&Xa[(size_t)row * KA + col]);
        else          v = ld4(&Xb[(size_t)row * (K - KA) + (col - KA)]);
      }
      xT[c4 + 0][r] = v.x; xT[c4 + 1][r] = v.y;
      xT[c4 + 2][r] = v.z; xT[c4 + 3][r] = v.w;
    }
    // stage W: wT[k][j]
    for (int idx = tid; idx < JP * (DKC / 4); idx += 256) {
      int j = idx >> 3;
      int c4 = (idx & 7) * 4;
      float4 v = make_float4(0.f, 0.f, 0.f, 0.f);
      if (j < JR) v = *(const float4*)&W[(size_t)j * K + kc + c4];
      wT[c4 + 0][j] = v.x; wT[c4 + 1][j] = v.y;
      wT[c4 + 2][j] = v.z; wT[c4 + 3][j] = v.w;
    }
    __syncthreads();
#pragma unroll 4
    for (int k = 0; k < DKC; ++k) {
      float4 xf = *(const float4*)&xT[k][tx * 4];
      float wf[CT];
      if (CT % 4 == 0) {
#pragma unroll
        for (int c = 0; c < CT; c += 4) {
          float4 wv = *(const float4*)&wT[k][ty * CT + c];
          wf[c] = wv.x; wf[c + 1] = wv.y; wf[c + 2] = wv.z; wf[c + 3] = wv.w;
        }
      } else {
#pragma unroll
        for (int c = 0; c < CT; ++c) wf[c] = wT[k][ty * CT + c];
      }
      float xr[4] = {xf.x, xf.y, xf.z, xf.w};
#pragma unroll
      for (int r = 0; r < 4; ++r)
#pragma unroll
        for (int c = 0; c < CT; ++c) acc[r][c] = fmaf(xr[r], wf[c], acc[r][c]);
    }
  }
  // epilogue
#pragma unroll
  for (int c = 0; c < CT; ++c) {
    int j = ty * CT + c;
    if (j >= JR) continue;
    float sc = 0.f, sh = 0.f;
    if (ACT == 1) {
      sc = bg[j] * rsqrtf(bv[j] + 1e-5f);
      sh = (lb[j] - bm[j]) * sc + bb[j];
    } else {
      sh = lb[j];
    }
#pragma unroll
    for (int r = 0; r < 4; ++r) {
      int row = r0 + tx * 4 + r;
      if (row >= NN) continue;
      float a = acc[r][c];
      float y;
      if (ACT == 0)      y = a + sh;
      else if (ACT == 1) y = fmaxf(fmaf(a, sc, sh), 0.f);
      else               y = gelu_exact(a + sh);
      if (RESID) y += resid[(size_t)row * JR + j];
      st1(&out[(size_t)row * JR + j], y);
    }
  }
}

// ---------------- att2 (64 -> 11) + softmax, one thread per node ----------------
__global__ __launch_bounds__(64) void att2_softmax_kernel(const float* __restrict__ g,
                                                          const float* __restrict__ W2,
                                                          const float* __restrict__ b2,
                                                          float* __restrict__ attw, int n_rows) {
  __shared__ float gl[64][65];
  int r0 = blockIdx.x * 64;
  for (int idx = threadIdx.x; idx < 64 * 16; idx += 64) {
    int r = idx >> 4, c4 = (idx & 15) * 4;
    float4 v = make_float4(0.f, 0.f, 0.f, 0.f);
    if (r0 + r < n_rows) v = *(const float4*)&g[(size_t)(r0 + r) * 64 + c4];
    gl[r][c4] = v.x; gl[r][c4 + 1] = v.y; gl[r][c4 + 2] = v.z; gl[r][c4 + 3] = v.w;
  }
  __syncthreads();
  int r = threadIdx.x;
  int n = r0 + r;
  if (n >= n_rows) return;
  float a[KIT + 1];
#pragma unroll
  for (int j = 0; j < KIT + 1; ++j) {
    float acc = b2[j];
#pragma unroll
    for (int k = 0; k < 64; ++k) acc = fmaf(gl[r][k], W2[j * 64 + k], acc);
    a[j] = acc;
  }
  float m = a[0];
#pragma unroll
  for (int j = 1; j < KIT + 1; ++j) m = fmaxf(m, a[j]);
  float s = 0.f;
#pragma unroll
  for (int j = 0; j < KIT + 1; ++j) { a[j] = expf(a[j] - m); s += a[j]; }
  float inv = 1.f / s;
#pragma unroll
  for (int j = 0; j < KIT + 1; ++j) attw[n * 16 + j] = a[j] * inv;
}

// ---------------- fuse: fused[n][128] = sum_k attw[n][k] * XS_k[n] (fp16 snapshots) ----
__global__ __launch_bounds__(256) void fused_gather_kernel(const __half* __restrict__ XS,
                                                           const float* __restrict__ attw,
                                                           float* __restrict__ fused) {
  int node = __builtin_amdgcn_readfirstlane((int)blockIdx.x * 4 + (int)(threadIdx.x >> 6));
  if (node >= NN) return;
  int lane = threadIdx.x & 63;
  float ax = 0.f, ay = 0.f;
#pragma unroll
  for (int k = 0; k <= KIT; ++k) {
    float wk = attw[node * 16 + k];   // wave-uniform -> s_load
    float2 v = __half22float2(((const __half2*)(XS + (size_t)k * NHF))[(size_t)node * 64 + lane]);
    ax = fmaf(wk, v.x, ax);
    ay = fmaf(wk, v.y, ay);
  }
  ((float2*)fused)[(size_t)node * 64 + lane] = make_float2(ax, ay);
}

// recompute-path variant: fused (+)= attw[:,k] * h (h fp16)
__global__ __launch_bounds__(256) void fused_accum_kernel(const __half* __restrict__ h,
                                                          const float* __restrict__ attw,
                                                          float* __restrict__ fused, int k) {
  int node = __builtin_amdgcn_readfirstlane((int)blockIdx.x * 4 + (int)(threadIdx.x >> 6));
  if (node >= NN) return;
  int lane = threadIdx.x & 63;
  float wk = attw[node * 16 + k];
  float2 v = __half22float2(((const __half2*)h)[(size_t)node * 64 + lane]);
  float2 o;
  if (k == 0) {
    o = make_float2(wk * v.x, wk * v.y);
  } else {
    float2 f = ((const float2*)fused)[(size_t)node * 64 + lane];
    o = make_float2(fmaf(wk, v.x, f.x), fmaf(wk, v.y, f.y));
  }
  ((float2*)fused)[(size_t)node * 64 + lane] = o;
}

extern "C" void kernel_launch(void* const* d_in, const int* in_sizes, int n_in,
                              void* d_out, int out_size, void* d_ws, size_t ws_size,
                              hipStream_t stream) {
  (void)in_sizes; (void)n_in; (void)out_size;
  const float* x      = (const float*)d_in[0];
  const int*   ei     = (const int*)d_in[1];
  const float* ew     = (const float*)d_in[2];
  const float* lin1_w = (const float*)d_in[3];
  const float* lin1_b = (const float*)d_in[4];
  const float* bn1_g  = (const float*)d_in[5];
  const float* bn1_b  = (const float*)d_in[6];
  const float* bn1_m  = (const float*)d_in[7];
  const float* bn1_v  = (const float*)d_in[8];
  const float* lin2_w = (const float*)d_in[9];
  const float* lin2_b = (const float*)d_in[10];
  const float* bn2_g  = (const float*)d_in[11];
  const float* bn2_b  = (const float*)d_in[12];
  const float* bn2_m  = (const float*)d_in[13];
  const float* bn2_v  = (const float*)d_in[14];
  const float* att1_w = (const float*)d_in[15];
  const float* att1_b = (const float*)d_in[16];
  const float* att2_w = (const float*)d_in[17];
  const float* att2_b = (const float*)d_in[18];
  const float* head1_w= (const float*)d_in[19];
  const float* head1_b= (const float*)d_in[20];
  const float* bn3_g  = (const float*)d_in[21];
  const float* bn3_b  = (const float*)d_in[22];
  const float* bn3_m  = (const float*)d_in[23];
  const float* bn3_v  = (const float*)d_in[24];
  const float* head2_w= (const float*)d_in[25];
  const float* head2_b= (const float*)d_in[26];
  float* out = (float*)d_out;

  char* p = (char*)d_ws;
  auto alloc = [&](size_t bytes) -> void* {
    void* r = (void*)p;
    p += (bytes + 255) & ~(size_t)255;
    return r;
  };
  float* wsum     = (float*)alloc((size_t)NN * 4);
  int*   deg      = (int*)alloc((size_t)NN * 4);
  int*   row_start= (int*)alloc((size_t)(NN + 1) * 4);
  int*   cursor   = (int*)alloc((size_t)NN * 4);
  int*   bsum     = (int*)alloc((size_t)256 * 4);
  int*   boff     = (int*)alloc((size_t)256 * 4);
  long*  csr      = (long*)alloc((size_t)EE * 8);
  float* gbuf     = (float*)alloc((size_t)NN * AHD * 4);
  float* attw     = (float*)alloc((size_t)NN * 16 * 4);
  float* fused    = (float*)alloc((size_t)NN * HH * 4);  // also stem h1 (fp32 row-major)
  float* zbuf     = (float*)alloc((size_t)NN * AHD * 4);
  size_t common = (size_t)(p - (char*)d_ws);
  size_t stored_need = common + (size_t)(KIT + 1) * NHF * 2 + 4096;
  bool stored = ws_size >= stored_need;

  const int GE = (EE + 255) / 256;         // edge-parallel grid
  const int GN = (NN + 255) / 256;         // node-parallel grid (196)
  const int GD = (NN + DRT - 1) / DRT;     // dense grid (782)
  const int GP = (NN + 3) / 4;             // wave-per-node grids (12500)
  const int GA = (NN + 63) / 64;           // att2 grid

  // graph preprocessing
  zero_kernel<<<GN, 256, 0, stream>>>(wsum, deg, NN);
  edge_stats_kernel<<<GE, 256, 0, stream>>>(ei, ew, wsum, deg, EE);
  scan1_kernel<<<GN, 256, 0, stream>>>(deg, bsum, NN);
  scan2_kernel<<<1, 256, 0, stream>>>(bsum, boff, row_start, GN, NN);
  scan3_kernel<<<GN, 256, 0, stream>>>(deg, boff, row_start, cursor, NN);
  csr_fill_kernel<<<GE, 256, 0, stream>>>(ei, ew, wsum, cursor, (int2*)csr, EE);

  if (stored) {
    __half* XS = (__half*)alloc((size_t)(KIT + 1) * NHF * 2);  // fp16 snapshots; XS0 = base
    // stem: h1 -> fused (fp32), base -> XS slot 0 (fp16)
    dense_kernel<128, 128, 128, 128, 1, false, float, float><<<GD, 256, 0, stream>>>(
        x, (const float*)nullptr, lin1_w, lin1_b, bn1_g, bn1_b, bn1_m, bn1_v, nullptr, fused);
    dense_kernel<128, 128, 128, 128, 1, true, float, __half><<<GD, 256, 0, stream>>>(
        fused, (const float*)nullptr, lin2_w, lin2_b, bn2_g, bn2_b, bn2_m, bn2_v, fused, XS);
    for (int k = 0; k < KIT; ++k) {
      prop_kernel<<<GP, 256, 0, stream>>>(XS + (size_t)k * NHF, XS, row_start,
                                          csr, XS + (size_t)(k + 1) * NHF);
    }
    // attention: ctx = [xs0, xs10] (fp16)
    dense_kernel<256, 128, 64, 64, 2, false, __half, float><<<GD, 256, 0, stream>>>(
        XS, XS + (size_t)KIT * NHF, att1_w, att1_b, nullptr, nullptr, nullptr, nullptr,
        nullptr, gbuf);
    att2_softmax_kernel<<<GA, 64, 0, stream>>>(gbuf, att2_w, att2_b, attw, NN);
    fused_gather_kernel<<<GP, 256, 0, stream>>>(XS, attw, fused);
  } else {
    __half* base = (__half*)alloc((size_t)NHF * 2);
    __half* hA   = (__half*)alloc((size_t)NHF * 2);
    __half* hB   = (__half*)alloc((size_t)NHF * 2);
    dense_kernel<128, 128, 128, 128, 1, false, float, float><<<GD, 256, 0, stream>>>(
        x, (const float*)nullptr, lin1_w, lin1_b, bn1_g, bn1_b, bn1_m, bn1_v, nullptr, fused);
    dense_kernel<128, 128, 128, 128, 1, true, float, __half><<<GD, 256, 0, stream>>>(
        fused, (const float*)nullptr, lin2_w, lin2_b, bn2_g, bn2_b, bn2_m, bn2_v, fused, base);
    // pass 1: get xs10
    const __half* cur = base;
    for (int k = 1; k <= KIT; ++k) {
      __half* nxt = (k & 1) ? hA : hB;
      prop_kernel<<<GP, 256, 0, stream>>>(cur, base, row_start, csr, nxt);
      cur = nxt;
    }
    dense_kernel<256, 128, 64, 64, 2, false, __half, float><<<GD, 256, 0, stream>>>(
        base, cur, att1_w, att1_b, nullptr, nullptr, nullptr, nullptr, nullptr, gbuf);
    att2_softmax_kernel<<<GA, 64, 0, stream>>>(gbuf, att2_w, att2_b, attw, NN);
    // pass 2: re-propagate, accumulate fused on the fly
    fused_accum_kernel<<<GP, 256, 0, stream>>>(base, attw, fused, 0);
    cur = base;
    for (int k = 1; k <= KIT; ++k) {
      __half* nxt = (k & 1) ? hA : hB;
      prop_kernel<<<GP, 256, 0, stream>>>(cur, base, row_start, csr, nxt);
      fused_accum_kernel<<<GP, 256, 0, stream>>>(nxt, attw, fused, k);
      cur = nxt;
    }
  }

  // heads (fused fp32 -> zbuf fp32 -> out)
  dense_kernel<128, 128, 64, 64, 1, false, float, float><<<GD, 256, 0, stream>>>(
      fused, (const float*)nullptr, head1_w, head1_b, bn3_g, bn3_b, bn3_m, bn3_v, nullptr, zbuf);
  dense_kernel<64, 64, 48, 40, 0, false, float, float><<<GD, 256, 0, stream>>>(
      zbuf, (const float*)nullptr, head2_w, head2_b, nullptr, nullptr, nullptr, nullptr, nullptr, out);
}

// Round 5
// 636.877 us; speedup vs baseline: 6.7076x; 1.2208x over previous
//
#include <hip/hip_runtime.h>
#include <hip/hip_fp16.h>
#include <math.h>

#define NN 50000
#define EE 800000
#define HH 128
#define KIT 10
#define NHF (NN * HH)     // 6,400,000 elements per snapshot

typedef _Float16 half8 __attribute__((ext_vector_type(8)));
typedef float floatx4 __attribute__((ext_vector_type(4)));

__device__ __forceinline__ float gelu_exact(float x) {
  return 0.5f * x * (1.f + erff(x * 0.70710678118654752f));
}

// typed 4-float load/store helpers (fp32 or fp16 storage)
__device__ __forceinline__ float4 ld4(const float* p) { return *(const float4*)p; }
__device__ __forceinline__ float4 ld4(const __half* p) {
  const __half2* q = (const __half2*)p;
  float2 lo = __half22float2(q[0]);
  float2 hi = __half22float2(q[1]);
  return make_float4(lo.x, lo.y, hi.x, hi.y);
}
__device__ __forceinline__ void st1(float* p, float v) { *p = v; }
__device__ __forceinline__ void st1(__half* p, float v) { *p = __float2half_rn(v); }

// ---------------- graph preprocessing ----------------
__global__ __launch_bounds__(256) void zero_kernel(float* __restrict__ wsum,
                                                   int* __restrict__ deg, int n) {
  int i = blockIdx.x * 256 + threadIdx.x;
  if (i < n) { wsum[i] = 0.f; deg[i] = 0; }
}

// also emits per-edge rank within its destination bucket (removes csr_fill atomic)
__global__ __launch_bounds__(256) void edge_stats_kernel(const int* __restrict__ ei,
                                                         const float* __restrict__ ew,
                                                         float* __restrict__ wsum,
                                                         int* __restrict__ deg,
                                                         int* __restrict__ rank, int e_cnt) {
  int e = blockIdx.x * 256 + threadIdx.x;
  if (e >= e_cnt) return;
  atomicAdd(&wsum[ei[e]], ew[e]);                 // out-weight sum by source (row)
  rank[e] = atomicAdd(&deg[ei[EE + e]], 1);       // in-degree by destination (col)
}

// multi-block scan: block sums -> scan partials -> local writeback
__global__ __launch_bounds__(256) void scan1_kernel(const int* __restrict__ deg,
                                                    int* __restrict__ bsum, int n) {
  __shared__ int red[256];
  int i = blockIdx.x * 256 + threadIdx.x;
  red[threadIdx.x] = (i < n) ? deg[i] : 0;
  __syncthreads();
  for (int off = 128; off > 0; off >>= 1) {
    if (threadIdx.x < off) red[threadIdx.x] += red[threadIdx.x + off];
    __syncthreads();
  }
  if (threadIdx.x == 0) bsum[blockIdx.x] = red[0];
}

__global__ __launch_bounds__(256) void scan2_kernel(const int* __restrict__ bsum,
                                                    int* __restrict__ boff,
                                                    int* __restrict__ row_start, int nb, int n) {
  __shared__ int buf[256];
  int tid = threadIdx.x;
  int v = (tid < nb) ? bsum[tid] : 0;
  buf[tid] = v;
  __syncthreads();
  for (int off = 1; off < 256; off <<= 1) {
    int t = (tid >= off) ? buf[tid - off] : 0;
    __syncthreads();
    buf[tid] += t;
    __syncthreads();
  }
  if (tid < nb) boff[tid] = buf[tid] - v;  // exclusive prefix
  if (tid == 255) row_start[n] = buf[255];
}

__global__ __launch_bounds__(256) void scan3_kernel(const int* __restrict__ deg,
                                                    const int* __restrict__ boff,
                                                    int* __restrict__ row_start, int n) {
  __shared__ int buf[256];
  int tid = threadIdx.x;
  int i = blockIdx.x * 256 + tid;
  int v = (i < n) ? deg[i] : 0;
  buf[tid] = v;
  __syncthreads();
  for (int off = 1; off < 256; off <<= 1) {
    int t = (tid >= off) ? buf[tid - off] : 0;
    __syncthreads();
    buf[tid] += t;
    __syncthreads();
  }
  if (i < n) row_start[i] = boff[blockIdx.x] + buf[tid] - v;
}

__global__ __launch_bounds__(256) void csr_fill_kernel(const int* __restrict__ ei,
                                                       const float* __restrict__ ew,
                                                       const float* __restrict__ wsum,
                                                       const int* __restrict__ row_start,
                                                       const int* __restrict__ rank,
                                                       int2* __restrict__ csr, int e_cnt) {
  int e = blockIdx.x * 256 + threadIdx.x;
  if (e >= e_cnt) return;
  int r = ei[e], c = ei[EE + e];
  float ws = wsum[r];
  ws = ws < 1.f ? 1.f : ws;
  float v = 0.9f * ew[e] / ws;            // (1-ALPHA) * enorm folded together
  int pos = row_start[c] + rank[e];       // no atomic
  csr[pos] = make_int2(r, __float_as_int(v));
}

// ---------------- propagation: one wave per node, fp16 h, half2 per lane ----------------
__global__ __launch_bounds__(256) void prop_kernel(const __half* __restrict__ h_cur,
                                                   const __half* __restrict__ base,
                                                   const int* __restrict__ row_start,
                                                   const long* __restrict__ csr,
                                                   __half* __restrict__ h_next) {
  int node = __builtin_amdgcn_readfirstlane((int)blockIdx.x * 4 + (int)(threadIdx.x >> 6));
  if (node >= NN) return;
  int lane = threadIdx.x & 63;
  const __half2* hc = (const __half2*)h_cur;
  float2 b = __half22float2(((const __half2*)base)[(size_t)node * 64 + lane]);
  float ax = 0.1f * b.x, ay = 0.1f * b.y;   // ALPHA * base
  float bx = 0.f, by = 0.f;
  int s = row_start[node], e = row_start[node + 1];
  int i = s;
  for (; i + 8 <= e; i += 8) {
    long c[8];
#pragma unroll
    for (int j = 0; j < 8; ++j) c[j] = csr[i + j];
    float2 g[8];
#pragma unroll
    for (int j = 0; j < 8; ++j) g[j] = __half22float2(hc[(size_t)(int)c[j] * 64 + lane]);
#pragma unroll
    for (int j = 0; j < 8; ++j) {
      float v = __int_as_float((int)(c[j] >> 32));
      if (j & 1) { bx = fmaf(v, g[j].x, bx); by = fmaf(v, g[j].y, by); }
      else       { ax = fmaf(v, g[j].x, ax); ay = fmaf(v, g[j].y, ay); }
    }
  }
  for (; i + 4 <= e; i += 4) {
    long c[4];
#pragma unroll
    for (int j = 0; j < 4; ++j) c[j] = csr[i + j];
    float2 g[4];
#pragma unroll
    for (int j = 0; j < 4; ++j) g[j] = __half22float2(hc[(size_t)(int)c[j] * 64 + lane]);
#pragma unroll
    for (int j = 0; j < 4; ++j) {
      float v = __int_as_float((int)(c[j] >> 32));
      if (j & 1) { bx = fmaf(v, g[j].x, bx); by = fmaf(v, g[j].y, by); }
      else       { ax = fmaf(v, g[j].x, ax); ay = fmaf(v, g[j].y, ay); }
    }
  }
  for (; i < e; ++i) {
    long c0 = csr[i];
    float2 g0 = __half22float2(hc[(size_t)(int)c0 * 64 + lane]);
    float v = __int_as_float((int)(c0 >> 32));
    ax = fmaf(v, g0.x, ax); ay = fmaf(v, g0.y, ay);
  }
  ((__half2*)h_next)[(size_t)node * 64 + lane] =
      __float22half2_rn(make_float2(ax + bx, ay + by));
}

// ---------------- MFMA dense: out[n][j] = act(sum_k X[n][k] * W[j][k] + ...) -------------
// Block 256 = 4 waves; tile 128 rows x JP cols; wave w owns rows [w*32, w*32+32).
// X and W staged fp16 in LDS (pad +8 halves -> 2-way max bank aliasing, free).
// v_mfma_f32_16x16x32_f16: A[m=lane&15][k=quad*8+j], B[n=lane&15][k=quad*8+j],
// C/D: col=lane&15, row=quad*4+reg (m89/m120-verified layouts).
template <int K, int KA, int JP, int JR, int ACT, bool RESID, typename IT, typename OT>
__global__ __launch_bounds__(256) void mfma_dense(
    const IT* __restrict__ Xa, const IT* __restrict__ Xb,
    const float* __restrict__ W, const float* __restrict__ lb,
    const float* __restrict__ bg, const float* __restrict__ bb,
    const float* __restrict__ bm, const float* __restrict__ bv,
    const OT* __restrict__ resid, OT* __restrict__ out) {
  constexpr int KC = (K > 128) ? 128 : K;
  static_assert(K % KC == 0 && KC % 32 == 0 && JP % 16 == 0, "");
  constexpr int JT = JP / 16;
  __shared__ _Float16 xL[128][KC + 8];
  __shared__ _Float16 wL[JP][KC + 8];
  const int tid = threadIdx.x;
  const int wv = tid >> 6, lane = tid & 63;
  const int q = lane >> 4, m = lane & 15;
  const int r0 = blockIdx.x * 128;

  floatx4 acc[2][JT];
#pragma unroll
  for (int rt = 0; rt < 2; ++rt)
#pragma unroll
    for (int jt = 0; jt < JT; ++jt) acc[rt][jt] = (floatx4)(0.f);

  for (int kc = 0; kc < K; kc += KC) {
    __syncthreads();
    // stage X: 128 rows x KC cols, fp16
    for (int idx = tid; idx < 128 * (KC / 4); idx += 256) {
      int r = idx / (KC / 4);
      int c4 = (idx % (KC / 4)) * 4;
      int row = r0 + r;
      int col = kc + c4;
      float4 v = make_float4(0.f, 0.f, 0.f, 0.f);
      if (row < NN) {
        if (col < KA) v = ld4(&Xa[(size_t)row * KA + col]);
        else          v = ld4(&Xb[(size_t)row * (K - KA) + (col - KA)]);
      }
      xL[r][c4 + 0] = (_Float16)v.x; xL[r][c4 + 1] = (_Float16)v.y;
      xL[r][c4 + 2] = (_Float16)v.z; xL[r][c4 + 3] = (_Float16)v.w;
    }
    // stage W: JP rows x KC cols, fp16 (zero-fill beyond JR)
    for (int idx = tid; idx < JP * (KC / 4); idx += 256) {
      int j = idx / (KC / 4);
      int c4 = (idx % (KC / 4)) * 4;
      float4 v = make_float4(0.f, 0.f, 0.f, 0.f);
      if (j < JR) v = *(const float4*)&W[(size_t)j * K + kc + c4];
      wL[j][c4 + 0] = (_Float16)v.x; wL[j][c4 + 1] = (_Float16)v.y;
      wL[j][c4 + 2] = (_Float16)v.z; wL[j][c4 + 3] = (_Float16)v.w;
    }
    __syncthreads();
#pragma unroll
    for (int ks = 0; ks < KC; ks += 32) {
      half8 a0 = *(const half8*)&xL[wv * 32 + m][ks + q * 8];
      half8 a1 = *(const half8*)&xL[wv * 32 + 16 + m][ks + q * 8];
#pragma unroll
      for (int jt = 0; jt < JT; ++jt) {
        half8 b = *(const half8*)&wL[jt * 16 + m][ks + q * 8];
        acc[0][jt] = __builtin_amdgcn_mfma_f32_16x16x32_f16(a0, b, acc[0][jt], 0, 0, 0);
        acc[1][jt] = __builtin_amdgcn_mfma_f32_16x16x32_f16(a1, b, acc[1][jt], 0, 0, 0);
      }
    }
  }
  // epilogue: lane holds col j = jt*16 + m, rows q*4 + reg (+16 per rt)
#pragma unroll
  for (int jt = 0; jt < JT; ++jt) {
    int j = jt * 16 + m;
    if (j >= JR) continue;
    float sc = 0.f, sh = 0.f;
    if (ACT == 1) {
      sc = bg[j] * rsqrtf(bv[j] + 1e-5f);
      sh = (lb[j] - bm[j]) * sc + bb[j];
    } else {
      sh = lb[j];
    }
#pragma unroll
    for (int rt = 0; rt < 2; ++rt) {
#pragma unroll
      for (int reg = 0; reg < 4; ++reg) {
        int row = r0 + wv * 32 + rt * 16 + q * 4 + reg;
        if (row >= NN) continue;
        float a = acc[rt][jt][reg];
        float y;
        if (ACT == 0)      y = a + sh;
        else if (ACT == 1) y = fmaxf(fmaf(a, sc, sh), 0.f);
        else               y = gelu_exact(a + sh);
        if (RESID) {
          float4 rv;  // scalar read via ld-helper pattern
          (void)rv;
          y += (float)resid[(size_t)row * JR + j];
        }
        st1(&out[(size_t)row * JR + j], y);
      }
    }
  }
}

// ---------------- att2 (64 -> 11) + softmax, one thread per node ----------------
__global__ __launch_bounds__(64) void att2_softmax_kernel(const __half* __restrict__ g,
                                                          const float* __restrict__ W2,
                                                          const float* __restrict__ b2,
                                                          float* __restrict__ attw, int n_rows) {
  __shared__ float gl[64][65];
  int r0 = blockIdx.x * 64;
  for (int idx = threadIdx.x; idx < 64 * 16; idx += 64) {
    int r = idx >> 4, c4 = (idx & 15) * 4;
    float4 v = make_float4(0.f, 0.f, 0.f, 0.f);
    if (r0 + r < n_rows) v = ld4(&g[(size_t)(r0 + r) * 64 + c4]);
    gl[r][c4] = v.x; gl[r][c4 + 1] = v.y; gl[r][c4 + 2] = v.z; gl[r][c4 + 3] = v.w;
  }
  __syncthreads();
  int r = threadIdx.x;
  int n = r0 + r;
  if (n >= n_rows) return;
  float a[KIT + 1];
#pragma unroll
  for (int j = 0; j < KIT + 1; ++j) {
    float acc = b2[j];
#pragma unroll
    for (int k = 0; k < 64; ++k) acc = fmaf(gl[r][k], W2[j * 64 + k], acc);
    a[j] = acc;
  }
  float mx = a[0];
#pragma unroll
  for (int j = 1; j < KIT + 1; ++j) mx = fmaxf(mx, a[j]);
  float s = 0.f;
#pragma unroll
  for (int j = 0; j < KIT + 1; ++j) { a[j] = expf(a[j] - mx); s += a[j]; }
  float inv = 1.f / s;
#pragma unroll
  for (int j = 0; j < KIT + 1; ++j) attw[n * 16 + j] = a[j] * inv;
}

// ---------------- fuse: fused[n][128] = sum_k attw[n][k] * XS_k[n] (fp16) ----------------
__global__ __launch_bounds__(256) void fused_gather_kernel(const __half* __restrict__ XS,
                                                           const float* __restrict__ attw,
                                                           __half* __restrict__ fused) {
  int node = __builtin_amdgcn_readfirstlane((int)blockIdx.x * 4 + (int)(threadIdx.x >> 6));
  if (node >= NN) return;
  int lane = threadIdx.x & 63;
  float ax = 0.f, ay = 0.f;
#pragma unroll
  for (int k = 0; k <= KIT; ++k) {
    float wk = attw[node * 16 + k];   // wave-uniform -> s_load
    float2 v = __half22float2(((const __half2*)(XS + (size_t)k * NHF))[(size_t)node * 64 + lane]);
    ax = fmaf(wk, v.x, ax);
    ay = fmaf(wk, v.y, ay);
  }
  ((__half2*)fused)[(size_t)node * 64 + lane] = __float22half2_rn(make_float2(ax, ay));
}

// recompute-path variant: fused (+)= attw[:,k] * h (h fp16, fused fp32 for accumulation)
__global__ __launch_bounds__(256) void fused_accum_kernel(const __half* __restrict__ h,
                                                          const float* __restrict__ attw,
                                                          float* __restrict__ fused, int k) {
  int node = __builtin_amdgcn_readfirstlane((int)blockIdx.x * 4 + (int)(threadIdx.x >> 6));
  if (node >= NN) return;
  int lane = threadIdx.x & 63;
  float wk = attw[node * 16 + k];
  float2 v = __half22float2(((const __half2*)h)[(size_t)node * 64 + lane]);
  float2 o;
  if (k == 0) {
    o = make_float2(wk * v.x, wk * v.y);
  } else {
    float2 f = ((const float2*)fused)[(size_t)node * 64 + lane];
    o = make_float2(fmaf(wk, v.x, f.x), fmaf(wk, v.y, f.y));
  }
  ((float2*)fused)[(size_t)node * 64 + lane] = o;
}

extern "C" void kernel_launch(void* const* d_in, const int* in_sizes, int n_in,
                              void* d_out, int out_size, void* d_ws, size_t ws_size,
                              hipStream_t stream) {
  (void)in_sizes; (void)n_in; (void)out_size;
  const float* x      = (const float*)d_in[0];
  const int*   ei     = (const int*)d_in[1];
  const float* ew     = (const float*)d_in[2];
  const float* lin1_w = (const float*)d_in[3];
  const float* lin1_b = (const float*)d_in[4];
  const float* bn1_g  = (const float*)d_in[5];
  const float* bn1_b  = (const float*)d_in[6];
  const float* bn1_m  = (const float*)d_in[7];
  const float* bn1_v  = (const float*)d_in[8];
  const float* lin2_w = (const float*)d_in[9];
  const float* lin2_b = (const float*)d_in[10];
  const float* bn2_g  = (const float*)d_in[11];
  const float* bn2_b  = (const float*)d_in[12];
  const float* bn2_m  = (const float*)d_in[13];
  const float* bn2_v  = (const float*)d_in[14];
  const float* att1_w = (const float*)d_in[15];
  const float* att1_b = (const float*)d_in[16];
  const float* att2_w = (const float*)d_in[17];
  const float* att2_b = (const float*)d_in[18];
  const float* head1_w= (const float*)d_in[19];
  const float* head1_b= (const float*)d_in[20];
  const float* bn3_g  = (const float*)d_in[21];
  const float* bn3_b  = (const float*)d_in[22];
  const float* bn3_m  = (const float*)d_in[23];
  const float* bn3_v  = (const float*)d_in[24];
  const float* head2_w= (const float*)d_in[25];
  const float* head2_b= (const float*)d_in[26];
  float* out = (float*)d_out;

  char* p = (char*)d_ws;
  auto alloc = [&](size_t bytes) -> void* {
    void* r = (void*)p;
    p += (bytes + 255) & ~(size_t)255;
    return r;
  };
  float* wsum     = (float*)alloc((size_t)NN * 4);
  int*   deg      = (int*)alloc((size_t)NN * 4);
  int*   row_start= (int*)alloc((size_t)(NN + 1) * 4);
  int*   rank     = (int*)alloc((size_t)EE * 4);
  int*   bsum     = (int*)alloc((size_t)256 * 4);
  int*   boff     = (int*)alloc((size_t)256 * 4);
  long*  csr      = (long*)alloc((size_t)EE * 8);
  __half* gbuf    = (__half*)alloc((size_t)NN * 64 * 2);
  float* attw     = (float*)alloc((size_t)NN * 16 * 4);
  __half* h1      = (__half*)alloc((size_t)NHF * 2);
  __half* fusedH  = (__half*)alloc((size_t)NHF * 2);
  __half* zbuf    = (__half*)alloc((size_t)NN * 64 * 2);
  size_t common = (size_t)(p - (char*)d_ws);
  size_t stored_need = common + (size_t)(KIT + 1) * NHF * 2 + 4096;
  bool stored = ws_size >= stored_need;

  const int GE = (EE + 255) / 256;         // edge-parallel grid
  const int GN = (NN + 255) / 256;         // node-parallel grid (196)
  const int GM = (NN + 127) / 128;         // mfma dense grid (391)
  const int GP = (NN + 3) / 4;             // wave-per-node grids (12500)
  const int GA = (NN + 63) / 64;           // att2 grid

  // graph preprocessing
  zero_kernel<<<GN, 256, 0, stream>>>(wsum, deg, NN);
  edge_stats_kernel<<<GE, 256, 0, stream>>>(ei, ew, wsum, deg, rank, EE);
  scan1_kernel<<<GN, 256, 0, stream>>>(deg, bsum, NN);
  scan2_kernel<<<1, 256, 0, stream>>>(bsum, boff, row_start, GN, NN);
  scan3_kernel<<<GN, 256, 0, stream>>>(deg, boff, row_start, NN);
  csr_fill_kernel<<<GE, 256, 0, stream>>>(ei, ew, wsum, row_start, rank, (int2*)csr, EE);

  if (stored) {
    __half* XS = (__half*)alloc((size_t)(KIT + 1) * NHF * 2);  // fp16 snapshots; XS0 = base
    mfma_dense<128, 128, 128, 128, 1, false, float, __half><<<GM, 256, 0, stream>>>(
        x, (const float*)nullptr, lin1_w, lin1_b, bn1_g, bn1_b, bn1_m, bn1_v, nullptr, h1);
    mfma_dense<128, 128, 128, 128, 1, true, __half, __half><<<GM, 256, 0, stream>>>(
        h1, (const __half*)nullptr, lin2_w, lin2_b, bn2_g, bn2_b, bn2_m, bn2_v, h1, XS);
    for (int k = 0; k < KIT; ++k) {
      prop_kernel<<<GP, 256, 0, stream>>>(XS + (size_t)k * NHF, XS, row_start,
                                          csr, XS + (size_t)(k + 1) * NHF);
    }
    mfma_dense<256, 128, 64, 64, 2, false, __half, __half><<<GM, 256, 0, stream>>>(
        XS, XS + (size_t)KIT * NHF, att1_w, att1_b, nullptr, nullptr, nullptr, nullptr,
        nullptr, gbuf);
    att2_softmax_kernel<<<GA, 64, 0, stream>>>(gbuf, att2_w, att2_b, attw, NN);
    fused_gather_kernel<<<GP, 256, 0, stream>>>(XS, attw, fusedH);
    mfma_dense<128, 128, 64, 64, 1, false, __half, __half><<<GM, 256, 0, stream>>>(
        fusedH, (const __half*)nullptr, head1_w, head1_b, bn3_g, bn3_b, bn3_m, bn3_v,
        nullptr, zbuf);
  } else {
    float*  fusedF = (float*)alloc((size_t)NHF * 4);
    __half* base   = (__half*)alloc((size_t)NHF * 2);
    __half* hA     = (__half*)alloc((size_t)NHF * 2);
    __half* hB     = (__half*)alloc((size_t)NHF * 2);
    mfma_dense<128, 128, 128, 128, 1, false, float, __half><<<GM, 256, 0, stream>>>(
        x, (const float*)nullptr, lin1_w, lin1_b, bn1_g, bn1_b, bn1_m, bn1_v, nullptr, h1);
    mfma_dense<128, 128, 128, 128, 1, true, __half, __half><<<GM, 256, 0, stream>>>(
        h1, (const __half*)nullptr, lin2_w, lin2_b, bn2_g, bn2_b, bn2_m, bn2_v, h1, base);
    // pass 1: get xs10
    const __half* cur = base;
    for (int k = 1; k <= KIT; ++k) {
      __half* nxt = (k & 1) ? hA : hB;
      prop_kernel<<<GP, 256, 0, stream>>>(cur, base, row_start, csr, nxt);
      cur = nxt;
    }
    mfma_dense<256, 128, 64, 64, 2, false, __half, __half><<<GM, 256, 0, stream>>>(
        base, cur, att1_w, att1_b, nullptr, nullptr, nullptr, nullptr, nullptr, gbuf);
    att2_softmax_kernel<<<GA, 64, 0, stream>>>(gbuf, att2_w, att2_b, attw, NN);
    // pass 2: re-propagate, accumulate fused on the fly (fp32 accumulator)
    fused_accum_kernel<<<GP, 256, 0, stream>>>(base, attw, fusedF, 0);
    cur = base;
    for (int k = 1; k <= KIT; ++k) {
      __half* nxt = (k & 1) ? hA : hB;
      prop_kernel<<<GP, 256, 0, stream>>>(cur, base, row_start, csr, nxt);
      fused_accum_kernel<<<GP, 256, 0, stream>>>(nxt, attw, fusedF, k);
      cur = nxt;
    }
    mfma_dense<128, 128, 64, 64, 1, false, float, __half><<<GM, 256, 0, stream>>>(
        fusedF, (const float*)nullptr, head1_w, head1_b, bn3_g, bn3_b, bn3_m, bn3_v,
        nullptr, zbuf);
  }

  // head2 (z fp16 -> out fp32)
  mfma_dense<64, 64, 48, 40, 0, false, __half, float><<<GM, 256, 0, stream>>>(
      zbuf, (const __half*)nullptr, head2_w, head2_b, nullptr, nullptr, nullptr, nullptr,
      nullptr, out);
}